// Round 9
// baseline (212.175 us; speedup 1.0000x reference)
//
#include <hip/hip_runtime.h>
#include <hip/hip_fp16.h>

#define NNODES 50000
#define NEDGES 800000
#define NSLOPE 0.2f
#define NBUCK 12500     // NNODES/4 buckets, 4 dsts each
#define BCAP 192        // slots per bucket (mean fill 64)

__device__ __forceinline__ float lrelu(float x) { return x > 0.f ? x : NSLOPE * x; }

// unpack 8 halves (uint4) and accumulate w * v into acc[0..7]
__device__ __forceinline__ void fma8(float* acc, uint4 v, float w) {
    __half2 p0 = *(__half2*)&v.x, p1 = *(__half2*)&v.y;
    __half2 p2 = *(__half2*)&v.z, p3 = *(__half2*)&v.w;
    float2 f;
    f = __half22float2(p0); acc[0] += w * f.x; acc[1] += w * f.y;
    f = __half22float2(p1); acc[2] += w * f.x; acc[3] += w * f.y;
    f = __half22float2(p2); acc[4] += w * f.x; acc[5] += w * f.y;
    f = __half22float2(p3); acc[6] += w * f.x; acc[7] += w * f.y;
}

// ---------------- fused GEMM + attention-dot ----------------
template<int NCOL, int HEADS>
__global__ __launch_bounds__(256) void gemm_att_kernel(
    const float* __restrict__ A, const float* __restrict__ W,
    const float* __restrict__ atts, const float* __restrict__ attd,
    __half* __restrict__ H, float* __restrict__ as_, float* __restrict__ ad_,
    int nrows) {
    constexpr int LG = NCOL / 4;
    constexpr int GROUPS = 256 / LG;
    constexpr int RPT = 64 / GROUPS;
    constexpr int CH = NCOL / HEADS;
    constexpr int HL = CH / 4;
    constexpr int LDAP = 132;
    __shared__ float Alds[64 * LDAP];
    int t = threadIdx.x;
    long r0 = (long)blockIdx.x * 64;
    long abase = r0 * 128;
    long alimit = (long)nrows * 128;
#pragma unroll
    for (int i = 0; i < 8; i++) {
        int off = i * 1024 + t * 4;
        float4 v = make_float4(0.f, 0.f, 0.f, 0.f);
        if (abase + off < alimit) v = *(const float4*)&A[abase + off];
        int row = off >> 7, col = off & 127;
        *(float4*)&Alds[row * LDAP + col] = v;
    }
    __syncthreads();

    int l = t % LG, g = t / LG;
    int c = l * 4;
    int rb = g * RPT;
    float4 acc[RPT];
#pragma unroll
    for (int i = 0; i < RPT; i++) acc[i] = make_float4(0.f, 0.f, 0.f, 0.f);

    for (int k0 = 0; k0 < 128; k0 += 4) {
        float4 w0 = *(const float4*)&W[(k0 + 0) * NCOL + c];
        float4 w1 = *(const float4*)&W[(k0 + 1) * NCOL + c];
        float4 w2 = *(const float4*)&W[(k0 + 2) * NCOL + c];
        float4 w3 = *(const float4*)&W[(k0 + 3) * NCOL + c];
#pragma unroll
        for (int i = 0; i < RPT; i++) {
            float4 a = *(const float4*)&Alds[(rb + i) * LDAP + k0];
            acc[i].x += a.x * w0.x + a.y * w1.x + a.z * w2.x + a.w * w3.x;
            acc[i].y += a.x * w0.y + a.y * w1.y + a.z * w2.y + a.w * w3.y;
            acc[i].z += a.x * w0.z + a.y * w1.z + a.z * w2.z + a.w * w3.z;
            acc[i].w += a.x * w0.w + a.y * w1.w + a.z * w2.w + a.w * w3.w;
        }
    }

    float4 asw = *(const float4*)&atts[c];
    float4 adw = *(const float4*)&attd[c];
#pragma unroll
    for (int i = 0; i < RPT; i++) {
        long row = r0 + rb + i;
        float ps = acc[i].x * asw.x + acc[i].y * asw.y + acc[i].z * asw.z + acc[i].w * asw.w;
        float pd = acc[i].x * adw.x + acc[i].y * adw.y + acc[i].z * adw.z + acc[i].w * adw.w;
#pragma unroll
        for (int m = 1; m < HL; m <<= 1) {
            ps += __shfl_xor(ps, m);
            pd += __shfl_xor(pd, m);
        }
        if (row < nrows) {
            __half2 p0 = __floats2half2_rn(acc[i].x, acc[i].y);
            __half2 p1 = __floats2half2_rn(acc[i].z, acc[i].w);
            uint2 pk = make_uint2(*(unsigned*)&p0, *(unsigned*)&p1);
            *(uint2*)&H[row * NCOL + c] = pk;
            if ((l & (HL - 1)) == 0) {
                int h = c / CH;
                as_[row * HEADS + h] = ps;
                ad_[row * HEADS + h] = pd;
            }
        }
    }
}

// ---------------- bucketed CSR build ----------------
// pass 1: XCD-partitioned append. Block part = blockIdx&7 (presumed XCD id)
// owns contiguous bucket range [part*NBUCK/8, (part+1)*NBUCK/8); grid-strides
// all edges, appends only its own buckets -> cursor/staging lines stay in ONE
// XCD's L2 (no cross-XCD line bouncing). Correctness mapping-independent.
__global__ __launch_bounds__(256) void bucket_append_kernel(
    const int* __restrict__ ei, int* __restrict__ bcursor, unsigned* __restrict__ staging) {
    const int part = blockIdx.x & 7;
    const int bip = blockIdx.x >> 3;            // block index within partition
    const int stride = (gridDim.x >> 3) * 256;  // threads per partition
    for (int e = bip * 256 + (int)threadIdx.x; e < NEDGES; e += stride) {
        int d = ei[NEDGES + e];
        int b = d >> 2;
        int p = (b * 8) / NBUCK;                // contiguous bucket-range partition
        if (p != part) continue;
        int s = ei[e];
        int pos = atomicAdd(&bcursor[b], 1);
        if (pos < BCAP) staging[(long)b * BCAP + pos] = (unsigned)s | ((unsigned)(d & 3) << 16);
    }
}

// pass 2: one wave per bucket: per-dst counts (register + shfl reduce)
__global__ __launch_bounds__(256) void bucket_count_kernel(
    const unsigned* __restrict__ staging, const int* __restrict__ bcursor,
    int* __restrict__ counts) {
    int w = threadIdx.x >> 6, lane = threadIdx.x & 63;
    int b = blockIdx.x * 4 + w;
    int n = bcursor[b]; if (n > BCAP) n = BCAP;
    int c0 = 0, c1 = 0, c2 = 0, c3 = 0;
    for (int i = lane; i < n; i += 64) {
        unsigned v = staging[(long)b * BCAP + i];
        int dl = (v >> 16) & 3;
        c0 += (dl == 0); c1 += (dl == 1); c2 += (dl == 2); c3 += (dl == 3);
    }
#pragma unroll
    for (int m = 1; m < 64; m <<= 1) {
        c0 += __shfl_xor(c0, m); c1 += __shfl_xor(c1, m);
        c2 += __shfl_xor(c2, m); c3 += __shfl_xor(c3, m);
    }
    if (lane < 4) {
        int cc = (lane == 0) ? c0 : (lane == 1) ? c1 : (lane == 2) ? c2 : c3;
        counts[b * 4 + lane] = cc;
    }
}

// ---------------- scans (offs, ends) ----------------
__global__ void scan1_kernel(const int* __restrict__ counts, int* __restrict__ offs,
                             int* __restrict__ bsums, int n) {
    __shared__ int tmp[256];
    int i = blockIdx.x * 256 + threadIdx.x;
    int v = (i < n) ? counts[i] : 0;
    tmp[threadIdx.x] = v;
    __syncthreads();
    for (int off = 1; off < 256; off <<= 1) {
        int t = (threadIdx.x >= off) ? tmp[threadIdx.x - off] : 0;
        __syncthreads();
        tmp[threadIdx.x] += t;
        __syncthreads();
    }
    if (i < n) offs[i] = tmp[threadIdx.x] - v;
    if (threadIdx.x == 255) bsums[blockIdx.x] = tmp[255];
}

__global__ void scan2_kernel(int* __restrict__ bsums, int nb) {
    __shared__ int tmp[256];
    int v = (threadIdx.x < nb) ? bsums[threadIdx.x] : 0;
    tmp[threadIdx.x] = v;
    __syncthreads();
    for (int off = 1; off < 256; off <<= 1) {
        int t = (threadIdx.x >= off) ? tmp[threadIdx.x - off] : 0;
        __syncthreads();
        tmp[threadIdx.x] += t;
        __syncthreads();
    }
    if (threadIdx.x < nb) bsums[threadIdx.x] = tmp[threadIdx.x] - v;
}

__global__ void scan3_kernel(int* __restrict__ offs, const int* __restrict__ bsums,
                             const int* __restrict__ counts, int* __restrict__ ends, int n) {
    int i = blockIdx.x * 256 + threadIdx.x;
    if (i >= n) return;
    int o = offs[i] + bsums[blockIdx.x];
    offs[i] = o;
    ends[i] = o + counts[i];
}

// pass 3: one wave per bucket: place entries via 4 LDS cursors; dense writes
__global__ __launch_bounds__(256) void bucket_scatter_kernel(
    const unsigned* __restrict__ staging, const int* __restrict__ bcursor,
    const int* __restrict__ offs, int* __restrict__ ssrc) {
    __shared__ int lcur[16];
    int w = threadIdx.x >> 6, lane = threadIdx.x & 63;
    int b = blockIdx.x * 4 + w;
    if (lane < 4) lcur[w * 4 + lane] = offs[b * 4 + lane];
    __syncthreads();
    int n = bcursor[b]; if (n > BCAP) n = BCAP;
    for (int i = lane; i < n; i += 64) {
        unsigned v = staging[(long)b * BCAP + i];
        int dl = (v >> 16) & 3;
        int pos = atomicAdd(&lcur[w * 4 + dl], 1);
        ssrc[pos] = (int)(v & 0xFFFFu);
    }
}

// ---------------- gather: one wave per dst node, fp16 rows ----------------
template<int HEADS, int NCOL, int LRELU>
__global__ __launch_bounds__(256) void gather_kernel(
    const int* __restrict__ ssrc, const int* __restrict__ offs,
    const int* __restrict__ ends, const float* __restrict__ as_,
    const float* __restrict__ ad_, const __half* __restrict__ H,
    const float* __restrict__ bias, float* __restrict__ out, int n) {
    constexpr int CHUNK = 64 / HEADS;
    constexpr int LPE = NCOL / 8;
    constexpr int EPI = 64 / LPE;
    int wave = (blockIdx.x * blockDim.x + threadIdx.x) >> 6;
    if (wave >= n) return;
    int lane = threadIdx.x & 63;
    int d = wave;
    int sub = lane / LPE;
    int c = (lane % LPE) * 8;
    int hc = (HEADS == 1) ? 0 : (c >> 5);
    int SB = hc * CHUNK;
    int pe = (HEADS == 1) ? lane : (lane % CHUNK);
    int ph = (HEADS == 1) ? 0 : (lane / CHUNK);
    float ad_p = ad_[d * HEADS + ph];
    float acc[8];
#pragma unroll
    for (int i = 0; i < 8; i++) acc[i] = 0.f;
    float dsum = 0.f;
    int start = offs[d], end = ends[d];

    int base = start;
    int m = end - base; if (m > CHUNK) m = CHUNK;
    int sv = 0; float wv = 0.f;
    if (m > 0) {
        if (pe < m) {
            sv = ssrc[base + pe];
            wv = __expf(lrelu(as_[sv * HEADS + ph] + ad_p));
        }
        dsum += wv;
    }
    while (m > 0) {
        int nbase = base + CHUNK;
        int nm = end - nbase; if (nm > CHUNK) nm = CHUNK;
        int svn = 0;
        if (nm > 0 && pe < nm) svn = ssrc[nbase + pe];
        int i = 0;
        for (; i + 4 * EPI <= m; i += 4 * EPI) {
            int i0 = i + sub, i1 = i + EPI + sub, i2 = i + 2 * EPI + sub, i3 = i + 3 * EPI + sub;
            int s0 = __shfl(sv, SB + i0);
            int s1 = __shfl(sv, SB + i1);
            int s2 = __shfl(sv, SB + i2);
            int s3 = __shfl(sv, SB + i3);
            uint4 v0 = *(const uint4*)&H[(long)s0 * NCOL + c];
            uint4 v1 = *(const uint4*)&H[(long)s1 * NCOL + c];
            uint4 v2 = *(const uint4*)&H[(long)s2 * NCOL + c];
            uint4 v3 = *(const uint4*)&H[(long)s3 * NCOL + c];
            float w0 = __shfl(wv, SB + i0);
            float w1 = __shfl(wv, SB + i1);
            float w2 = __shfl(wv, SB + i2);
            float w3 = __shfl(wv, SB + i3);
            fma8(acc, v0, w0); fma8(acc, v1, w1);
            fma8(acc, v2, w2); fma8(acc, v3, w3);
        }
        for (; i < m; i += EPI) {
            int idx = i + sub;
            int cl = (idx < m) ? idx : (m - 1);
            int s = __shfl(sv, SB + cl);
            float w = __shfl(wv, SB + cl);
            if (idx >= m) w = 0.f;
            uint4 v = *(const uint4*)&H[(long)s * NCOL + c];
            fma8(acc, v, w);
        }
        if (nm <= 0) break;
        float wvn = 0.f;
        if (pe < nm) wvn = __expf(lrelu(as_[svn * HEADS + ph] + ad_p));
        dsum += wvn;
        sv = svn; wv = wvn; m = nm; base = nbase;
    }

    if (HEADS == 1) {
#pragma unroll
        for (int msk = 1; msk < 64; msk <<= 1) dsum += __shfl_xor(dsum, msk);
    } else {
#pragma unroll
        for (int msk = 1; msk < 16; msk <<= 1) dsum += __shfl_xor(dsum, msk);
        dsum = __shfl(dsum, SB);
    }
#pragma unroll
    for (int msk = LPE; msk < 64; msk <<= 1) {
#pragma unroll
        for (int i = 0; i < 8; i++) acc[i] += __shfl_xor(acc[i], msk);
    }
    {
        float wself = __expf(lrelu(as_[d * HEADS + hc] + ad_[d * HEADS + hc]));
        dsum += wself;
        uint4 vs = *(const uint4*)&H[(long)d * NCOL + c];
        fma8(acc, vs, wself);
    }
    float inv = 1.f / (dsum + 1e-16f);
    if (lane < LPE) {
        float4 r0, r1;
        r0.x = acc[0] * inv + bias[c + 0]; r0.y = acc[1] * inv + bias[c + 1];
        r0.z = acc[2] * inv + bias[c + 2]; r0.w = acc[3] * inv + bias[c + 3];
        r1.x = acc[4] * inv + bias[c + 4]; r1.y = acc[5] * inv + bias[c + 5];
        r1.z = acc[6] * inv + bias[c + 6]; r1.w = acc[7] * inv + bias[c + 7];
        if (LRELU) {
            r0.x = lrelu(r0.x); r0.y = lrelu(r0.y); r0.z = lrelu(r0.z); r0.w = lrelu(r0.w);
            r1.x = lrelu(r1.x); r1.y = lrelu(r1.y); r1.z = lrelu(r1.z); r1.w = lrelu(r1.w);
        }
        *(float4*)&out[(long)d * NCOL + c] = r0;
        *(float4*)&out[(long)d * NCOL + c + 4] = r1;
    }
}

static inline int nblk(long total) { return (int)((total + 255) / 256); }

extern "C" void kernel_launch(void* const* d_in, const int* in_sizes, int n_in,
                              void* d_out, int out_size, void* d_ws, size_t ws_size,
                              hipStream_t stream) {
    const float* x    = (const float*)d_in[0];
    const int*   ei   = (const int*)d_in[1];   // [2, NEDGES]
    const float* W1   = (const float*)d_in[2];
    const float* as1w = (const float*)d_in[3];
    const float* ad1w = (const float*)d_in[4];
    const float* b1   = (const float*)d_in[5];
    const float* W2   = (const float*)d_in[6];
    const float* as2w = (const float*)d_in[7];
    const float* ad2w = (const float*)d_in[8];
    const float* b2   = (const float*)d_in[9];
    float* out = (float*)d_out;

    char* wsb = (char*)d_ws;
    size_t o = 0;
    __half* h1    = (__half*)(wsb + o); o += (size_t)NNODES * 128 * 2;   // 12.8 MB; h2 aliases
    float* x2     = (float*)(wsb + o);  o += (size_t)NNODES * 128 * 4;   // 25.6 MB
    float* a_src1 = (float*)(wsb + o);  o += (size_t)NNODES * 4 * 4;
    float* a_dst1 = (float*)(wsb + o);  o += (size_t)NNODES * 4 * 4;
    float* a_src2 = (float*)(wsb + o);  o += (size_t)NNODES * 4;
    float* a_dst2 = (float*)(wsb + o);  o += (size_t)NNODES * 4;
    int* counts  = (int*)(wsb + o); o += (size_t)NNODES * 4;
    int* offs    = (int*)(wsb + o); o += (size_t)NNODES * 4;
    int* ends    = (int*)(wsb + o); o += (size_t)NNODES * 4;
    int* bsums   = (int*)(wsb + o); o += 1024;
    int* ssrc    = (int*)(wsb + o); o += (size_t)NEDGES * 4;
    int* bcursor = (int*)(wsb + o); o += (size_t)NBUCK * 4;
    unsigned* staging = (unsigned*)(wsb + o); o += (size_t)NBUCK * BCAP * 4;  // 9.6 MB
    __half* h2 = h1;

    const int NB = (NNODES + 255) / 256;   // 196
    const int GB = (NNODES + 63) / 64;     // 782
    const int BB = NBUCK / 4;              // 3125 (wave per bucket)

    // ---- bucketed CSR build ----
    hipMemsetAsync(bcursor, 0, sizeof(int) * NBUCK, stream);
    bucket_append_kernel<<<2048, 256, 0, stream>>>(ei, bcursor, staging);
    bucket_count_kernel<<<BB, 256, 0, stream>>>(staging, bcursor, counts);
    scan1_kernel<<<NB, 256, 0, stream>>>(counts, offs, bsums, NNODES);
    scan2_kernel<<<1, 256, 0, stream>>>(bsums, NB);
    scan3_kernel<<<NB, 256, 0, stream>>>(offs, bsums, counts, ends, NNODES);
    bucket_scatter_kernel<<<BB, 256, 0, stream>>>(staging, bcursor, offs, ssrc);

    // ---- layer 1 ----
    gemm_att_kernel<128, 4><<<GB, 256, 0, stream>>>(x, W1, as1w, ad1w, h1, a_src1, a_dst1, NNODES);
    gather_kernel<4, 128, 1><<<nblk((long)NNODES * 64), 256, 0, stream>>>(
        ssrc, offs, ends, a_src1, a_dst1, h1, b1, x2, NNODES);

    // ---- layer 2 ----
    gemm_att_kernel<64, 1><<<GB, 256, 0, stream>>>(x2, W2, as2w, ad2w, h2, a_src2, a_dst2, NNODES);
    gather_kernel<1, 64, 0><<<nblk((long)NNODES * 64), 256, 0, stream>>>(
        ssrc, offs, ends, a_src2, a_dst2, h2, b2, out, NNODES);
}

// Round 10
// 168.563 us; speedup vs baseline: 1.2587x; 1.2587x over previous
//
#include <hip/hip_runtime.h>
#include <hip/hip_fp16.h>

#define NNODES 50000
#define NEDGES 800000
#define NSLOPE 0.2f
#define NB2 782        // buckets of 64 dsts: ceil(50000/64)
#define BCAP2 1280     // slots per bucket (mean 1024, +8 sigma)
#define CSRB 256       // CSR histogram blocks
#define EPB 3125       // edges per CSR block (256*3125 = 800000)

__device__ __forceinline__ float lrelu(float x) { return x > 0.f ? x : NSLOPE * x; }

// unpack 8 halves (uint4) and accumulate w * v into acc[0..7]
__device__ __forceinline__ void fma8(float* acc, uint4 v, float w) {
    __half2 p0 = *(__half2*)&v.x, p1 = *(__half2*)&v.y;
    __half2 p2 = *(__half2*)&v.z, p3 = *(__half2*)&v.w;
    float2 f;
    f = __half22float2(p0); acc[0] += w * f.x; acc[1] += w * f.y;
    f = __half22float2(p1); acc[2] += w * f.x; acc[3] += w * f.y;
    f = __half22float2(p2); acc[4] += w * f.x; acc[5] += w * f.y;
    f = __half22float2(p3); acc[6] += w * f.x; acc[7] += w * f.y;
}

// ---------------- GEMM + attention-dot body (device fn) ----------------
template<int NCOL, int HEADS>
__device__ void gemm_att_body(int bid, const float* __restrict__ A, const float* __restrict__ W,
                              const float* __restrict__ atts, const float* __restrict__ attd,
                              __half* __restrict__ H, float* __restrict__ as_,
                              float* __restrict__ ad_, int nrows) {
    constexpr int LG = NCOL / 4;
    constexpr int GROUPS = 256 / LG;
    constexpr int RPT = 64 / GROUPS;
    constexpr int CH = NCOL / HEADS;
    constexpr int HL = CH / 4;
    constexpr int LDAP = 132;
    __shared__ float Alds[64 * LDAP];
    int t = threadIdx.x;
    long r0 = (long)bid * 64;
    long abase = r0 * 128;
    long alimit = (long)nrows * 128;
#pragma unroll
    for (int i = 0; i < 8; i++) {
        int off = i * 1024 + t * 4;
        float4 v = make_float4(0.f, 0.f, 0.f, 0.f);
        if (abase + off < alimit) v = *(const float4*)&A[abase + off];
        int row = off >> 7, col = off & 127;
        *(float4*)&Alds[row * LDAP + col] = v;
    }
    __syncthreads();

    int l = t % LG, g = t / LG;
    int c = l * 4;
    int rb = g * RPT;
    float4 acc[RPT];
#pragma unroll
    for (int i = 0; i < RPT; i++) acc[i] = make_float4(0.f, 0.f, 0.f, 0.f);

    for (int k0 = 0; k0 < 128; k0 += 4) {
        float4 w0 = *(const float4*)&W[(k0 + 0) * NCOL + c];
        float4 w1 = *(const float4*)&W[(k0 + 1) * NCOL + c];
        float4 w2 = *(const float4*)&W[(k0 + 2) * NCOL + c];
        float4 w3 = *(const float4*)&W[(k0 + 3) * NCOL + c];
#pragma unroll
        for (int i = 0; i < RPT; i++) {
            float4 a = *(const float4*)&Alds[(rb + i) * LDAP + k0];
            acc[i].x += a.x * w0.x + a.y * w1.x + a.z * w2.x + a.w * w3.x;
            acc[i].y += a.x * w0.y + a.y * w1.y + a.z * w2.y + a.w * w3.y;
            acc[i].z += a.x * w0.z + a.y * w1.z + a.z * w2.z + a.w * w3.z;
            acc[i].w += a.x * w0.w + a.y * w1.w + a.z * w2.w + a.w * w3.w;
        }
    }

    float4 asw = *(const float4*)&atts[c];
    float4 adw = *(const float4*)&attd[c];
#pragma unroll
    for (int i = 0; i < RPT; i++) {
        long row = r0 + rb + i;
        float ps = acc[i].x * asw.x + acc[i].y * asw.y + acc[i].z * asw.z + acc[i].w * asw.w;
        float pd = acc[i].x * adw.x + acc[i].y * adw.y + acc[i].z * adw.z + acc[i].w * adw.w;
#pragma unroll
        for (int m = 1; m < HL; m <<= 1) {
            ps += __shfl_xor(ps, m);
            pd += __shfl_xor(pd, m);
        }
        if (row < nrows) {
            __half2 p0 = __floats2half2_rn(acc[i].x, acc[i].y);
            __half2 p1 = __floats2half2_rn(acc[i].z, acc[i].w);
            uint2 pk = make_uint2(*(unsigned*)&p0, *(unsigned*)&p1);
            *(uint2*)&H[row * NCOL + c] = pk;
            if ((l & (HL - 1)) == 0) {
                int h = c / CH;
                as_[row * HEADS + h] = ps;
                ad_[row * HEADS + h] = pd;
            }
        }
    }
}

// ---------------- fused: CSR hist+reserve+place (blocks 0..255) | GEMM1 (blocks 256+) ----
// CSR path: 2-pass LDS aggregation. ~768 global atomics per block instead of 3125.
__global__ __launch_bounds__(256) void fused_csr_gemm1_kernel(
    const int* __restrict__ ei, int* __restrict__ bcursor, unsigned* __restrict__ staging,
    const float* __restrict__ A, const float* __restrict__ W,
    const float* __restrict__ atts, const float* __restrict__ attd,
    __half* __restrict__ H, float* __restrict__ as_, float* __restrict__ ad_, int nrows) {
    if (blockIdx.x >= CSRB) {
        gemm_att_body<128, 4>(blockIdx.x - CSRB, A, W, atts, attd, H, as_, ad_, nrows);
        return;
    }
    __shared__ int hist[NB2];
    __shared__ int hbase[NB2];
    int tid = threadIdx.x;
    for (int i = tid; i < NB2; i += 256) hist[i] = 0;
    __syncthreads();
    int e0 = blockIdx.x * EPB;
#pragma unroll
    for (int i = 0; i < 13; i++) {
        int e = e0 + i * 256 + tid;
        if (e < e0 + EPB) {
            int d = ei[NEDGES + e];
            atomicAdd(&hist[d >> 6], 1);
        }
    }
    __syncthreads();
    for (int i = tid; i < NB2; i += 256) {
        int cnt = hist[i];
        hbase[i] = cnt ? atomicAdd(&bcursor[i], cnt) : 0;   // ONE global atomic per bucket
        hist[i] = 0;
    }
    __syncthreads();
#pragma unroll
    for (int i = 0; i < 13; i++) {
        int e = e0 + i * 256 + tid;
        if (e < e0 + EPB) {
            int d = ei[NEDGES + e];
            int s = ei[e];
            int b = d >> 6;
            int r = atomicAdd(&hist[b], 1);
            int pos = hbase[b] + r;
            if (pos < BCAP2)
                staging[(long)b * BCAP2 + pos] = (unsigned)s | ((unsigned)(d & 63) << 16);
        }
    }
}

// ---------------- per-dst counts: one block per 64-dst bucket ----------------
__global__ __launch_bounds__(256) void bucket_count2_kernel(
    const unsigned* __restrict__ staging, const int* __restrict__ bcursor,
    int* __restrict__ counts) {
    __shared__ int cnt[64];
    int b = blockIdx.x;
    if (threadIdx.x < 64) cnt[threadIdx.x] = 0;
    __syncthreads();
    int n = bcursor[b]; if (n > BCAP2) n = BCAP2;
    for (int i = threadIdx.x; i < n; i += 256) {
        unsigned v = staging[(long)b * BCAP2 + i];
        atomicAdd(&cnt[(v >> 16) & 63], 1);
    }
    __syncthreads();
    if (threadIdx.x < 64) {
        int d = b * 64 + threadIdx.x;
        if (d < NNODES) counts[d] = cnt[threadIdx.x];
    }
}

// ---------------- scans (offs, ends) ----------------
__global__ void scan1_kernel(const int* __restrict__ counts, int* __restrict__ offs,
                             int* __restrict__ bsums, int n) {
    __shared__ int tmp[256];
    int i = blockIdx.x * 256 + threadIdx.x;
    int v = (i < n) ? counts[i] : 0;
    tmp[threadIdx.x] = v;
    __syncthreads();
    for (int off = 1; off < 256; off <<= 1) {
        int t = (threadIdx.x >= off) ? tmp[threadIdx.x - off] : 0;
        __syncthreads();
        tmp[threadIdx.x] += t;
        __syncthreads();
    }
    if (i < n) offs[i] = tmp[threadIdx.x] - v;
    if (threadIdx.x == 255) bsums[blockIdx.x] = tmp[255];
}

__global__ void scan2_kernel(int* __restrict__ bsums, int nb) {
    __shared__ int tmp[256];
    int v = (threadIdx.x < nb) ? bsums[threadIdx.x] : 0;
    tmp[threadIdx.x] = v;
    __syncthreads();
    for (int off = 1; off < 256; off <<= 1) {
        int t = (threadIdx.x >= off) ? tmp[threadIdx.x - off] : 0;
        __syncthreads();
        tmp[threadIdx.x] += t;
        __syncthreads();
    }
    if (threadIdx.x < nb) bsums[threadIdx.x] = tmp[threadIdx.x] - v;
}

__global__ void scan3_kernel(int* __restrict__ offs, const int* __restrict__ bsums,
                             const int* __restrict__ counts, int* __restrict__ ends, int n) {
    int i = blockIdx.x * 256 + threadIdx.x;
    if (i >= n) return;
    int o = offs[i] + bsums[blockIdx.x];
    offs[i] = o;
    ends[i] = o + counts[i];
}

// ---------------- final scatter: one block per 64-dst bucket ----------------
__global__ __launch_bounds__(256) void bucket_scatter2_kernel(
    const unsigned* __restrict__ staging, const int* __restrict__ bcursor,
    const int* __restrict__ offs, int* __restrict__ ssrc) {
    __shared__ int cur[64];
    int b = blockIdx.x;
    if (threadIdx.x < 64) {
        int d = b * 64 + threadIdx.x;
        cur[threadIdx.x] = (d < NNODES) ? offs[d] : 0;
    }
    __syncthreads();
    int n = bcursor[b]; if (n > BCAP2) n = BCAP2;
    for (int i = threadIdx.x; i < n; i += 256) {
        unsigned v = staging[(long)b * BCAP2 + i];
        int dl = (v >> 16) & 63;
        int pos = atomicAdd(&cur[dl], 1);
        ssrc[pos] = (int)(v & 0xFFFFu);
    }
}

// ---------------- standalone GEMM (layer 2) ----------------
template<int NCOL, int HEADS>
__global__ __launch_bounds__(256) void gemm_att_kernel(
    const float* __restrict__ A, const float* __restrict__ W,
    const float* __restrict__ atts, const float* __restrict__ attd,
    __half* __restrict__ H, float* __restrict__ as_, float* __restrict__ ad_,
    int nrows) {
    gemm_att_body<NCOL, HEADS>(blockIdx.x, A, W, atts, attd, H, as_, ad_, nrows);
}

// ---------------- gather: one wave per dst node, fp16 rows ----------------
template<int HEADS, int NCOL, int LRELU>
__global__ __launch_bounds__(256) void gather_kernel(
    const int* __restrict__ ssrc, const int* __restrict__ offs,
    const int* __restrict__ ends, const float* __restrict__ as_,
    const float* __restrict__ ad_, const __half* __restrict__ H,
    const float* __restrict__ bias, float* __restrict__ out, int n) {
    constexpr int CHUNK = 64 / HEADS;
    constexpr int LPE = NCOL / 8;
    constexpr int EPI = 64 / LPE;
    int wave = (blockIdx.x * blockDim.x + threadIdx.x) >> 6;
    if (wave >= n) return;
    int lane = threadIdx.x & 63;
    int d = wave;
    int sub = lane / LPE;
    int c = (lane % LPE) * 8;
    int hc = (HEADS == 1) ? 0 : (c >> 5);
    int SB = hc * CHUNK;
    int pe = (HEADS == 1) ? lane : (lane % CHUNK);
    int ph = (HEADS == 1) ? 0 : (lane / CHUNK);
    float ad_p = ad_[d * HEADS + ph];
    float acc[8];
#pragma unroll
    for (int i = 0; i < 8; i++) acc[i] = 0.f;
    float dsum = 0.f;
    int start = offs[d], end = ends[d];

    int base = start;
    int m = end - base; if (m > CHUNK) m = CHUNK;
    int sv = 0; float wv = 0.f;
    if (m > 0) {
        if (pe < m) {
            sv = ssrc[base + pe];
            wv = __expf(lrelu(as_[sv * HEADS + ph] + ad_p));
        }
        dsum += wv;
    }
    while (m > 0) {
        int nbase = base + CHUNK;
        int nm = end - nbase; if (nm > CHUNK) nm = CHUNK;
        int svn = 0;
        if (nm > 0 && pe < nm) svn = ssrc[nbase + pe];
        int i = 0;
        for (; i + 4 * EPI <= m; i += 4 * EPI) {
            int i0 = i + sub, i1 = i + EPI + sub, i2 = i + 2 * EPI + sub, i3 = i + 3 * EPI + sub;
            int s0 = __shfl(sv, SB + i0);
            int s1 = __shfl(sv, SB + i1);
            int s2 = __shfl(sv, SB + i2);
            int s3 = __shfl(sv, SB + i3);
            uint4 v0 = *(const uint4*)&H[(long)s0 * NCOL + c];
            uint4 v1 = *(const uint4*)&H[(long)s1 * NCOL + c];
            uint4 v2 = *(const uint4*)&H[(long)s2 * NCOL + c];
            uint4 v3 = *(const uint4*)&H[(long)s3 * NCOL + c];
            float w0 = __shfl(wv, SB + i0);
            float w1 = __shfl(wv, SB + i1);
            float w2 = __shfl(wv, SB + i2);
            float w3 = __shfl(wv, SB + i3);
            fma8(acc, v0, w0); fma8(acc, v1, w1);
            fma8(acc, v2, w2); fma8(acc, v3, w3);
        }
        for (; i < m; i += EPI) {
            int idx = i + sub;
            int cl = (idx < m) ? idx : (m - 1);
            int s = __shfl(sv, SB + cl);
            float w = __shfl(wv, SB + cl);
            if (idx >= m) w = 0.f;
            uint4 v = *(const uint4*)&H[(long)s * NCOL + c];
            fma8(acc, v, w);
        }
        if (nm <= 0) break;
        float wvn = 0.f;
        if (pe < nm) wvn = __expf(lrelu(as_[svn * HEADS + ph] + ad_p));
        dsum += wvn;
        sv = svn; wv = wvn; m = nm; base = nbase;
    }

    if (HEADS == 1) {
#pragma unroll
        for (int msk = 1; msk < 64; msk <<= 1) dsum += __shfl_xor(dsum, msk);
    } else {
#pragma unroll
        for (int msk = 1; msk < 16; msk <<= 1) dsum += __shfl_xor(dsum, msk);
        dsum = __shfl(dsum, SB);
    }
#pragma unroll
    for (int msk = LPE; msk < 64; msk <<= 1) {
#pragma unroll
        for (int i = 0; i < 8; i++) acc[i] += __shfl_xor(acc[i], msk);
    }
    {
        float wself = __expf(lrelu(as_[d * HEADS + hc] + ad_[d * HEADS + hc]));
        dsum += wself;
        uint4 vs = *(const uint4*)&H[(long)d * NCOL + c];
        fma8(acc, vs, wself);
    }
    float inv = 1.f / (dsum + 1e-16f);
    if (lane < LPE) {
        float4 r0, r1;
        r0.x = acc[0] * inv + bias[c + 0]; r0.y = acc[1] * inv + bias[c + 1];
        r0.z = acc[2] * inv + bias[c + 2]; r0.w = acc[3] * inv + bias[c + 3];
        r1.x = acc[4] * inv + bias[c + 4]; r1.y = acc[5] * inv + bias[c + 5];
        r1.z = acc[6] * inv + bias[c + 6]; r1.w = acc[7] * inv + bias[c + 7];
        if (LRELU) {
            r0.x = lrelu(r0.x); r0.y = lrelu(r0.y); r0.z = lrelu(r0.z); r0.w = lrelu(r0.w);
            r1.x = lrelu(r1.x); r1.y = lrelu(r1.y); r1.z = lrelu(r1.z); r1.w = lrelu(r1.w);
        }
        *(float4*)&out[(long)d * NCOL + c] = r0;
        *(float4*)&out[(long)d * NCOL + c + 4] = r1;
    }
}

static inline int nblk(long total) { return (int)((total + 255) / 256); }

extern "C" void kernel_launch(void* const* d_in, const int* in_sizes, int n_in,
                              void* d_out, int out_size, void* d_ws, size_t ws_size,
                              hipStream_t stream) {
    const float* x    = (const float*)d_in[0];
    const int*   ei   = (const int*)d_in[1];   // [2, NEDGES]
    const float* W1   = (const float*)d_in[2];
    const float* as1w = (const float*)d_in[3];
    const float* ad1w = (const float*)d_in[4];
    const float* b1   = (const float*)d_in[5];
    const float* W2   = (const float*)d_in[6];
    const float* as2w = (const float*)d_in[7];
    const float* ad2w = (const float*)d_in[8];
    const float* b2   = (const float*)d_in[9];
    float* out = (float*)d_out;

    char* wsb = (char*)d_ws;
    size_t o = 0;
    __half* h1    = (__half*)(wsb + o); o += (size_t)NNODES * 128 * 2;   // 12.8 MB; h2 aliases
    float* x2     = (float*)(wsb + o);  o += (size_t)NNODES * 128 * 4;   // 25.6 MB
    float* a_src1 = (float*)(wsb + o);  o += (size_t)NNODES * 4 * 4;
    float* a_dst1 = (float*)(wsb + o);  o += (size_t)NNODES * 4 * 4;
    float* a_src2 = (float*)(wsb + o);  o += (size_t)NNODES * 4;
    float* a_dst2 = (float*)(wsb + o);  o += (size_t)NNODES * 4;
    int* counts  = (int*)(wsb + o); o += (size_t)NNODES * 4;
    int* offs    = (int*)(wsb + o); o += (size_t)NNODES * 4;
    int* ends    = (int*)(wsb + o); o += (size_t)NNODES * 4;
    int* bsums   = (int*)(wsb + o); o += 1024;
    int* ssrc    = (int*)(wsb + o); o += (size_t)NEDGES * 4;
    int* bcursor = (int*)(wsb + o); o += (size_t)((NB2 + 2) & ~1) * 4;
    unsigned* staging = (unsigned*)(wsb + o); o += (size_t)NB2 * BCAP2 * 4;  // 4 MB
    __half* h2 = h1;

    const int NB = (NNODES + 255) / 256;   // 196
    const int GB = (NNODES + 63) / 64;     // 782

    // ---- CSR build + GEMM1 (fused) ----
    hipMemsetAsync(bcursor, 0, sizeof(int) * NB2, stream);
    fused_csr_gemm1_kernel<<<CSRB + GB, 256, 0, stream>>>(
        ei, bcursor, staging, x, W1, as1w, ad1w, h1, a_src1, a_dst1, NNODES);
    bucket_count2_kernel<<<NB2, 256, 0, stream>>>(staging, bcursor, counts);
    scan1_kernel<<<NB, 256, 0, stream>>>(counts, offs, bsums, NNODES);
    scan2_kernel<<<1, 256, 0, stream>>>(bsums, NB);
    scan3_kernel<<<NB, 256, 0, stream>>>(offs, bsums, counts, ends, NNODES);
    bucket_scatter2_kernel<<<NB2, 256, 0, stream>>>(staging, bcursor, offs, ssrc);

    // ---- layer 1 gather ----
    gather_kernel<4, 128, 1><<<nblk((long)NNODES * 64), 256, 0, stream>>>(
        ssrc, offs, ends, a_src1, a_dst1, h1, b1, x2, NNODES);

    // ---- layer 2 ----
    gemm_att_kernel<64, 1><<<GB, 256, 0, stream>>>(x2, W2, as2w, ad2w, h2, a_src2, a_dst2, NNODES);
    gather_kernel<1, 64, 0><<<nblk((long)NNODES * 64), 256, 0, stream>>>(
        ssrc, offs, ends, a_src2, a_dst2, h2, b2, out, NNODES);
}

// Round 11
// 161.587 us; speedup vs baseline: 1.3131x; 1.0432x over previous
//
#include <hip/hip_runtime.h>
#include <hip/hip_fp16.h>

#define NNODES 50000
#define NEDGES 800000
#define NSLOPE 0.2f
#define NB2 782        // buckets of 64 dsts: ceil(50000/64)
#define BCAP2 1280     // ssrc slots per bucket (mean 1024, +8 sigma)
#define CSRB 256       // CSR sort blocks
#define EPB 3125       // edges per CSR block (256*3125 = 800000)

__device__ __forceinline__ float lrelu(float x) { return x > 0.f ? x : NSLOPE * x; }

// unpack 8 halves (uint4) and accumulate w * v into acc[0..7]
__device__ __forceinline__ void fma8(float* acc, uint4 v, float w) {
    __half2 p0 = *(__half2*)&v.x, p1 = *(__half2*)&v.y;
    __half2 p2 = *(__half2*)&v.z, p3 = *(__half2*)&v.w;
    float2 f;
    f = __half22float2(p0); acc[0] += w * f.x; acc[1] += w * f.y;
    f = __half22float2(p1); acc[2] += w * f.x; acc[3] += w * f.y;
    f = __half22float2(p2); acc[4] += w * f.x; acc[5] += w * f.y;
    f = __half22float2(p3); acc[6] += w * f.x; acc[7] += w * f.y;
}

// ---------------- GEMM + attention-dot body (LDS passed in) ----------------
template<int NCOL, int HEADS>
__device__ void gemm_att_body(int bid, float* __restrict__ Alds,
                              const float* __restrict__ A, const float* __restrict__ W,
                              const float* __restrict__ atts, const float* __restrict__ attd,
                              __half* __restrict__ H, float* __restrict__ as_,
                              float* __restrict__ ad_, int nrows) {
    constexpr int LG = NCOL / 4;
    constexpr int GROUPS = 256 / LG;
    constexpr int RPT = 64 / GROUPS;
    constexpr int CH = NCOL / HEADS;
    constexpr int HL = CH / 4;
    constexpr int LDAP = 132;
    int t = threadIdx.x;
    long r0 = (long)bid * 64;
    long abase = r0 * 128;
    long alimit = (long)nrows * 128;
#pragma unroll
    for (int i = 0; i < 8; i++) {
        int off = i * 1024 + t * 4;
        float4 v = make_float4(0.f, 0.f, 0.f, 0.f);
        if (abase + off < alimit) v = *(const float4*)&A[abase + off];
        int row = off >> 7, col = off & 127;
        *(float4*)&Alds[row * LDAP + col] = v;
    }
    __syncthreads();

    int l = t % LG, g = t / LG;
    int c = l * 4;
    int rb = g * RPT;
    float4 acc[RPT];
#pragma unroll
    for (int i = 0; i < RPT; i++) acc[i] = make_float4(0.f, 0.f, 0.f, 0.f);

    for (int k0 = 0; k0 < 128; k0 += 4) {
        float4 w0 = *(const float4*)&W[(k0 + 0) * NCOL + c];
        float4 w1 = *(const float4*)&W[(k0 + 1) * NCOL + c];
        float4 w2 = *(const float4*)&W[(k0 + 2) * NCOL + c];
        float4 w3 = *(const float4*)&W[(k0 + 3) * NCOL + c];
#pragma unroll
        for (int i = 0; i < RPT; i++) {
            float4 a = *(const float4*)&Alds[(rb + i) * LDAP + k0];
            acc[i].x += a.x * w0.x + a.y * w1.x + a.z * w2.x + a.w * w3.x;
            acc[i].y += a.x * w0.y + a.y * w1.y + a.z * w2.y + a.w * w3.y;
            acc[i].z += a.x * w0.z + a.y * w1.z + a.z * w2.z + a.w * w3.z;
            acc[i].w += a.x * w0.w + a.y * w1.w + a.z * w2.w + a.w * w3.w;
        }
    }

    float4 asw = *(const float4*)&atts[c];
    float4 adw = *(const float4*)&attd[c];
#pragma unroll
    for (int i = 0; i < RPT; i++) {
        long row = r0 + rb + i;
        float ps = acc[i].x * asw.x + acc[i].y * asw.y + acc[i].z * asw.z + acc[i].w * asw.w;
        float pd = acc[i].x * adw.x + acc[i].y * adw.y + acc[i].z * adw.z + acc[i].w * adw.w;
#pragma unroll
        for (int m = 1; m < HL; m <<= 1) {
            ps += __shfl_xor(ps, m);
            pd += __shfl_xor(pd, m);
        }
        if (row < nrows) {
            __half2 p0 = __floats2half2_rn(acc[i].x, acc[i].y);
            __half2 p1 = __floats2half2_rn(acc[i].z, acc[i].w);
            uint2 pk = make_uint2(*(unsigned*)&p0, *(unsigned*)&p1);
            *(uint2*)&H[row * NCOL + c] = pk;
            if ((l & (HL - 1)) == 0) {
                int h = c / CH;
                as_[row * HEADS + h] = ps;
                ad_[row * HEADS + h] = pd;
            }
        }
    }
}

// ---------------- fused: block-local counting sort (blocks 0..255) | GEMM1 ----------------
// CSR path: zero global atomics. Each block sorts its 3125-edge segment by bucket in LDS,
// writes a private dense 12.5 KB entry segment + coalesced [block][bucket] count/offset rows.
__global__ __launch_bounds__(256) void fused_csr_gemm1_kernel(
    const int* __restrict__ ei, unsigned* __restrict__ priv,
    int* __restrict__ cnt_mtx, int* __restrict__ lofs_mtx,
    const float* __restrict__ A, const float* __restrict__ W,
    const float* __restrict__ atts, const float* __restrict__ attd,
    __half* __restrict__ H, float* __restrict__ as_, float* __restrict__ ad_, int nrows) {
    __shared__ float smem[64 * 132];   // union: GEMM tile | CSR {hist,lofs,sbuf}
    if (blockIdx.x >= CSRB) {
        gemm_att_body<128, 4>(blockIdx.x - CSRB, smem, A, W, atts, attd, H, as_, ad_, nrows);
        return;
    }
    int* hist = (int*)smem;        // [1024] (782 used)
    int* lofs = hist + 1024;       // [1024]
    int* sbuf = lofs + 1024;       // [256]
    int tid = threadIdx.x;
    for (int i = tid; i < 1024; i += 256) hist[i] = 0;
    __syncthreads();
    int e0 = blockIdx.x * EPB;
    int dreg[13];
#pragma unroll
    for (int i = 0; i < 13; i++) {
        int e = e0 + i * 256 + tid;
        dreg[i] = (e < e0 + EPB) ? ei[NEDGES + e] : -1;
        if (dreg[i] >= 0) atomicAdd(&hist[dreg[i] >> 6], 1);
    }
    __syncthreads();
    // exclusive scan over 1024 buckets (4 per thread + block scan of partials)
    int t4 = tid * 4;
    int a0 = hist[t4], a1 = hist[t4 + 1], a2 = hist[t4 + 2], a3 = hist[t4 + 3];
    int p1 = a0 + a1, p2 = p1 + a2, p3 = p2 + a3;
    sbuf[tid] = p3;
    __syncthreads();
    for (int off = 1; off < 256; off <<= 1) {
        int v = (tid >= off) ? sbuf[tid - off] : 0;
        __syncthreads();
        sbuf[tid] += v;
        __syncthreads();
    }
    int base = (tid > 0) ? sbuf[tid - 1] : 0;
    lofs[t4] = base; lofs[t4 + 1] = base + a0; lofs[t4 + 2] = base + p1; lofs[t4 + 3] = base + p2;
    // coalesced matrix rows (4 consecutive per thread)
#pragma unroll
    for (int j = 0; j < 4; j++) {
        int i = t4 + j;
        if (i < NB2) {
            cnt_mtx[(long)blockIdx.x * NB2 + i] = hist[i];
            lofs_mtx[(long)blockIdx.x * NB2 + i] = lofs[i];
        }
    }
    // reset hist -> rank counters
    hist[t4] = 0; hist[t4 + 1] = 0; hist[t4 + 2] = 0; hist[t4 + 3] = 0;
    __syncthreads();
    unsigned* seg = priv + (long)blockIdx.x * EPB;
#pragma unroll
    for (int i = 0; i < 13; i++) {
        if (dreg[i] >= 0) {
            int e = e0 + i * 256 + tid;
            int s = ei[e];
            int b = dreg[i] >> 6;
            int r = atomicAdd(&hist[b], 1);
            seg[lofs[b] + r] = (unsigned)s | ((unsigned)(dreg[i] & 63) << 16);
        }
    }
}

// ---------------- consumer: block per bucket -> dst-grouped ssrc + offs/ends ----------------
__global__ __launch_bounds__(256) void consumer_kernel(
    const unsigned* __restrict__ priv, const int* __restrict__ cnt_mtx,
    const int* __restrict__ lofs_mtx, int* __restrict__ ssrc,
    int* __restrict__ offs, int* __restrict__ ends) {
    __shared__ int dcnt[64], dbase[64], dcur[64];
    int b = blockIdx.x, tid = threadIdx.x;
    if (tid < 64) dcnt[tid] = 0;
    int cnt = cnt_mtx[(long)tid * NB2 + b];
    int lof = lofs_mtx[(long)tid * NB2 + b];
    const unsigned* seg = priv + (long)tid * EPB + lof;
    __syncthreads();
    for (int k = 0; k < cnt; k++) {
        unsigned v = seg[k];
        atomicAdd(&dcnt[(v >> 16) & 63], 1);
    }
    __syncthreads();
    if (tid < 64) {
        int v = dcnt[tid], p = v;
#pragma unroll
        for (int off = 1; off < 64; off <<= 1) {
            int u = __shfl_up(p, off);
            if (tid >= off) p += u;
        }
        dbase[tid] = p - v;
        dcur[tid] = p - v;
    }
    __syncthreads();
    int obase = b * BCAP2;
    for (int k = 0; k < cnt; k++) {
        unsigned v = seg[k];
        int dl = (v >> 16) & 63;
        int r = atomicAdd(&dcur[dl], 1);
        if (r < BCAP2) ssrc[obase + r] = (int)(v & 0xFFFFu);
    }
    __syncthreads();
    if (tid < 64) {
        int d = b * 64 + tid;
        if (d < NNODES) {
            int s0 = obase + dbase[tid];
            int e1 = s0 + dcnt[tid];
            int cap = obase + BCAP2;
            offs[d] = s0 < cap ? s0 : cap;
            ends[d] = e1 < cap ? e1 : cap;
        }
    }
}

// ---------------- standalone GEMM (layer 2) ----------------
template<int NCOL, int HEADS>
__global__ __launch_bounds__(256) void gemm_att_kernel(
    const float* __restrict__ A, const float* __restrict__ W,
    const float* __restrict__ atts, const float* __restrict__ attd,
    __half* __restrict__ H, float* __restrict__ as_, float* __restrict__ ad_,
    int nrows) {
    __shared__ float smem[64 * 132];
    gemm_att_body<NCOL, HEADS>(blockIdx.x, smem, A, W, atts, attd, H, as_, ad_, nrows);
}

// ---------------- gather: one wave per dst node, fp16 rows ----------------
template<int HEADS, int NCOL, int LRELU>
__global__ __launch_bounds__(256) void gather_kernel(
    const int* __restrict__ ssrc, const int* __restrict__ offs,
    const int* __restrict__ ends, const float* __restrict__ as_,
    const float* __restrict__ ad_, const __half* __restrict__ H,
    const float* __restrict__ bias, float* __restrict__ out, int n) {
    constexpr int CHUNK = 64 / HEADS;
    constexpr int LPE = NCOL / 8;
    constexpr int EPI = 64 / LPE;
    int wave = (blockIdx.x * blockDim.x + threadIdx.x) >> 6;
    if (wave >= n) return;
    int lane = threadIdx.x & 63;
    int d = wave;
    int sub = lane / LPE;
    int c = (lane % LPE) * 8;
    int hc = (HEADS == 1) ? 0 : (c >> 5);
    int SB = hc * CHUNK;
    int pe = (HEADS == 1) ? lane : (lane % CHUNK);
    int ph = (HEADS == 1) ? 0 : (lane / CHUNK);
    float ad_p = ad_[d * HEADS + ph];
    float acc[8];
#pragma unroll
    for (int i = 0; i < 8; i++) acc[i] = 0.f;
    float dsum = 0.f;
    int start = offs[d], end = ends[d];

    int base = start;
    int m = end - base; if (m > CHUNK) m = CHUNK;
    int sv = 0; float wv = 0.f;
    if (m > 0) {
        if (pe < m) {
            sv = ssrc[base + pe];
            wv = __expf(lrelu(as_[sv * HEADS + ph] + ad_p));
        }
        dsum += wv;
    }
    while (m > 0) {
        int nbase = base + CHUNK;
        int nm = end - nbase; if (nm > CHUNK) nm = CHUNK;
        int svn = 0;
        if (nm > 0 && pe < nm) svn = ssrc[nbase + pe];
        int i = 0;
        for (; i + 4 * EPI <= m; i += 4 * EPI) {
            int i0 = i + sub, i1 = i + EPI + sub, i2 = i + 2 * EPI + sub, i3 = i + 3 * EPI + sub;
            int s0 = __shfl(sv, SB + i0);
            int s1 = __shfl(sv, SB + i1);
            int s2 = __shfl(sv, SB + i2);
            int s3 = __shfl(sv, SB + i3);
            uint4 v0 = *(const uint4*)&H[(long)s0 * NCOL + c];
            uint4 v1 = *(const uint4*)&H[(long)s1 * NCOL + c];
            uint4 v2 = *(const uint4*)&H[(long)s2 * NCOL + c];
            uint4 v3 = *(const uint4*)&H[(long)s3 * NCOL + c];
            float w0 = __shfl(wv, SB + i0);
            float w1 = __shfl(wv, SB + i1);
            float w2 = __shfl(wv, SB + i2);
            float w3 = __shfl(wv, SB + i3);
            fma8(acc, v0, w0); fma8(acc, v1, w1);
            fma8(acc, v2, w2); fma8(acc, v3, w3);
        }
        for (; i < m; i += EPI) {
            int idx = i + sub;
            int cl = (idx < m) ? idx : (m - 1);
            int s = __shfl(sv, SB + cl);
            float w = __shfl(wv, SB + cl);
            if (idx >= m) w = 0.f;
            uint4 v = *(const uint4*)&H[(long)s * NCOL + c];
            fma8(acc, v, w);
        }
        if (nm <= 0) break;
        float wvn = 0.f;
        if (pe < nm) wvn = __expf(lrelu(as_[svn * HEADS + ph] + ad_p));
        dsum += wvn;
        sv = svn; wv = wvn; m = nm; base = nbase;
    }

    if (HEADS == 1) {
#pragma unroll
        for (int msk = 1; msk < 64; msk <<= 1) dsum += __shfl_xor(dsum, msk);
    } else {
#pragma unroll
        for (int msk = 1; msk < 16; msk <<= 1) dsum += __shfl_xor(dsum, msk);
        dsum = __shfl(dsum, SB);
    }
#pragma unroll
    for (int msk = LPE; msk < 64; msk <<= 1) {
#pragma unroll
        for (int i = 0; i < 8; i++) acc[i] += __shfl_xor(acc[i], msk);
    }
    {
        float wself = __expf(lrelu(as_[d * HEADS + hc] + ad_[d * HEADS + hc]));
        dsum += wself;
        uint4 vs = *(const uint4*)&H[(long)d * NCOL + c];
        fma8(acc, vs, wself);
    }
    float inv = 1.f / (dsum + 1e-16f);
    if (lane < LPE) {
        float4 r0, r1;
        r0.x = acc[0] * inv + bias[c + 0]; r0.y = acc[1] * inv + bias[c + 1];
        r0.z = acc[2] * inv + bias[c + 2]; r0.w = acc[3] * inv + bias[c + 3];
        r1.x = acc[4] * inv + bias[c + 4]; r1.y = acc[5] * inv + bias[c + 5];
        r1.z = acc[6] * inv + bias[c + 6]; r1.w = acc[7] * inv + bias[c + 7];
        if (LRELU) {
            r0.x = lrelu(r0.x); r0.y = lrelu(r0.y); r0.z = lrelu(r0.z); r0.w = lrelu(r0.w);
            r1.x = lrelu(r1.x); r1.y = lrelu(r1.y); r1.z = lrelu(r1.z); r1.w = lrelu(r1.w);
        }
        *(float4*)&out[(long)d * NCOL + c] = r0;
        *(float4*)&out[(long)d * NCOL + c + 4] = r1;
    }
}

static inline int nblk(long total) { return (int)((total + 255) / 256); }

extern "C" void kernel_launch(void* const* d_in, const int* in_sizes, int n_in,
                              void* d_out, int out_size, void* d_ws, size_t ws_size,
                              hipStream_t stream) {
    const float* x    = (const float*)d_in[0];
    const int*   ei   = (const int*)d_in[1];   // [2, NEDGES]
    const float* W1   = (const float*)d_in[2];
    const float* as1w = (const float*)d_in[3];
    const float* ad1w = (const float*)d_in[4];
    const float* b1   = (const float*)d_in[5];
    const float* W2   = (const float*)d_in[6];
    const float* as2w = (const float*)d_in[7];
    const float* ad2w = (const float*)d_in[8];
    const float* b2   = (const float*)d_in[9];
    float* out = (float*)d_out;

    char* wsb = (char*)d_ws;
    size_t o = 0;
    __half* h1    = (__half*)(wsb + o); o += (size_t)NNODES * 128 * 2;   // 12.8 MB; h2 aliases
    float* x2     = (float*)(wsb + o);  o += (size_t)NNODES * 128 * 4;   // 25.6 MB
    float* a_src1 = (float*)(wsb + o);  o += (size_t)NNODES * 4 * 4;
    float* a_dst1 = (float*)(wsb + o);  o += (size_t)NNODES * 4 * 4;
    float* a_src2 = (float*)(wsb + o);  o += (size_t)NNODES * 4;
    float* a_dst2 = (float*)(wsb + o);  o += (size_t)NNODES * 4;
    int* offs    = (int*)(wsb + o); o += (size_t)NNODES * 4;
    int* ends    = (int*)(wsb + o); o += (size_t)NNODES * 4;
    int* ssrc    = (int*)(wsb + o); o += (size_t)NB2 * BCAP2 * 4;        // 4.0 MB
    unsigned* priv = (unsigned*)(wsb + o); o += (size_t)CSRB * EPB * 4;  // 3.2 MB
    int* cnt_mtx  = (int*)(wsb + o); o += (size_t)CSRB * NB2 * 4;        // 0.8 MB
    int* lofs_mtx = (int*)(wsb + o); o += (size_t)CSRB * NB2 * 4;        // 0.8 MB
    __half* h2 = h1;

    const int GB = (NNODES + 63) / 64;     // 782

    // ---- CSR build (block-local sort) + GEMM1, fused; zero global atomics ----
    fused_csr_gemm1_kernel<<<CSRB + GB, 256, 0, stream>>>(
        ei, priv, cnt_mtx, lofs_mtx, x, W1, as1w, ad1w, h1, a_src1, a_dst1, NNODES);
    consumer_kernel<<<NB2, 256, 0, stream>>>(priv, cnt_mtx, lofs_mtx, ssrc, offs, ends);

    // ---- layer 1 gather ----
    gather_kernel<4, 128, 1><<<nblk((long)NNODES * 64), 256, 0, stream>>>(
        ssrc, offs, ends, a_src1, a_dst1, h1, b1, x2, NNODES);

    // ---- layer 2 ----
    gemm_att_kernel<64, 1><<<GB, 256, 0, stream>>>(x2, W2, as2w, ad2w, h2, a_src2, a_dst2, NNODES);
    gather_kernel<1, 64, 0><<<nblk((long)NNODES * 64), 256, 0, stream>>>(
        ssrc, offs, ends, a_src2, a_dst2, h2, b2, out, NNODES);
}